// Round 7
// baseline (333.870 us; speedup 1.0000x reference)
//
#include <hip/hip_runtime.h>
#include <hip/hip_bf16.h>

#define BB 8
#define NN 2048
#define CC 128
#define FF 128
#define ALPHA 0.2f
#define ROWS 16        // rows per k_out block
#define WTPAD 136      // padded LDS row stride in ushorts (272 B)
#define CHN 256        // chunks per batch
#define CLEN 8         // NN/CHN
#define CSH 3          // log2(CLEN)

typedef __hip_bfloat16 bf16;
typedef __attribute__((ext_vector_type(8))) short short8;   // 8 bf16 MFMA operand
typedef __attribute__((ext_vector_type(4))) float f32x4;    // MFMA accumulator

// ---------------- dtype helpers ----------------
__device__ __forceinline__ float ld1(const void* p, int i, int f32) {
    if (f32) return ((const float*)p)[i];
    return __bfloat162float(((const bf16*)p)[i]);
}
__device__ __forceinline__ float2 ld2(const void* p, int pair, int f32) {
    if (f32) return ((const float2*)p)[pair];
    __hip_bfloat162 v = ((const __hip_bfloat162*)p)[pair];
    return make_float2(__bfloat162float(v.x), __bfloat162float(v.y));
}

// ---------------- K_prep: flag + done-counters + wa + WT(bf16, f-major) ----------
__global__ __launch_bounds__(256) void k_prep(const void* __restrict__ text,
                                              const void* __restrict__ W,
                                              const void* __restrict__ a,
                                              int* __restrict__ flag,
                                              float* __restrict__ wa1,
                                              float* __restrict__ wa2,
                                              ushort* __restrict__ WT) {
    __shared__ int cnt;
    __shared__ float aL[2 * FF];
    const int t = threadIdx.x;
    if (t == 0) cnt = 0;
    __syncthreads();
    // dtype probe: fp32 low-half words decode as huge bf16 values
    const ushort2* p = (const ushort2*)text;
    int local = 0;
    for (int i = t; i < 1024; i += 256) {
        ushort2 v = p[i];
        float f = __uint_as_float(((unsigned)v.x) << 16);
        if (!(fabsf(f) <= 100.f)) local++;
    }
    atomicAdd(&cnt, local);
    __syncthreads();
    const int f32 = (cnt >= 64) ? 1 : 0;

    if (blockIdx.x == 0) {
        if (t == 0) flag[0] = f32;
        if (t >= 8 && t < 8 + BB) flag[t] = 0;     // done counters for k_ps
        aL[t] = ld1(a, t, f32);                    // t < 256 = 2F
        __syncthreads();
        if (t < CC) {
            float s1 = 0.f, s2 = 0.f;
            for (int f = 0; f < FF; f += 4) {
                float w0 = ld1(W, t * FF + f, f32);
                float w1 = ld1(W, t * FF + f + 1, f32);
                float w2 = ld1(W, t * FF + f + 2, f32);
                float w3 = ld1(W, t * FF + f + 3, f32);
                s1 += w0 * aL[f] + w1 * aL[f + 1] + w2 * aL[f + 2] + w3 * aL[f + 3];
                s2 += w0 * aL[FF + f] + w1 * aL[FF + f + 1] + w2 * aL[FF + f + 2] + w3 * aL[FF + f + 3];
            }
            wa1[t] = s1; wa2[t] = s2;
        }
    } else {
        // WT[f*CC+cc] = bf16(W[cc*FF+f])
        const int base = (blockIdx.x - 1) * 2048;
        for (int i = 0; i < 8; ++i) {
            int idx = base + i * 256 + t;          // idx = cc*FF + f
            int cc = idx >> 7, f = idx & 127;
            float v = ld1(W, idx, f32);
            bf16 b = __float2bfloat16(v);
            WT[f * CC + cc] = *(const ushort*)&b;
        }
    }
}

// ---------------- K_e: e1/e2 per row (wave per row) ----------------
__global__ __launch_bounds__(256) void k_e(const void* __restrict__ text,
                                           const float* __restrict__ wa1,
                                           const float* __restrict__ wa2,
                                           float* __restrict__ e1,
                                           float* __restrict__ e2,
                                           const int* __restrict__ flag) {
    const int f32 = *flag;
    const int wave = threadIdx.x >> 6;
    const int lane = threadIdx.x & 63;
    const int row = blockIdx.x * 4 + wave;
    float2 tv = ld2(text, row * (CC / 2) + lane, f32);
    float s1 = tv.x * wa1[2 * lane] + tv.y * wa1[2 * lane + 1];
    float s2 = tv.x * wa2[2 * lane] + tv.y * wa2[2 * lane + 1];
#pragma unroll
    for (int off = 32; off > 0; off >>= 1) {
        s1 += __shfl_down(s1, off, 64);
        s2 += __shfl_down(s2, off, 64);
    }
    if (lane == 0) { e1[row] = s1; e2[row] = s2; }
}

// ---------------- K_sort: LDS bitonic sort + wave-shuffle scans (R5 version) ------
__global__ __launch_bounds__(1024) void k_sort(const float* __restrict__ e2,
                                               float* __restrict__ e2s,
                                               int* __restrict__ sidx,
                                               float* __restrict__ z1,
                                               float* __restrict__ z2) {
    __shared__ float vals[NN];
    __shared__ int   idxs[NN];
    __shared__ float2 wtot[16];
    __shared__ float2 woff[16];
    const int b = blockIdx.x;
    const int t = threadIdx.x;

    for (int i = t; i < NN; i += 1024) { vals[i] = e2[b * NN + i]; idxs[i] = i; }
    __syncthreads();

    for (int size = 2; size <= NN; size <<= 1) {
        for (int stride = size >> 1; stride > 0; stride >>= 1) {
            int i = ((t & ~(stride - 1)) << 1) | (t & (stride - 1));
            int j = i | stride;
            bool up = ((i & size) == 0);
            float vi = vals[i], vj = vals[j];
            bool sw = up ? (vi > vj) : (vi < vj);
            if (sw) {
                vals[i] = vj; vals[j] = vi;
                int ti = idxs[i]; idxs[i] = idxs[j]; idxs[j] = ti;
            }
            __syncthreads();
        }
    }

    float v0 = vals[2 * t], v1 = vals[2 * t + 1];
    e2s[b * NN + 2 * t] = v0;
    e2s[b * NN + 2 * t + 1] = v1;
    sidx[b * NN + 2 * t] = idxs[2 * t];
    sidx[b * NN + 2 * t + 1] = idxs[2 * t + 1];

    // dual inclusive scan (exp(v), exp(.2v)) via wave shuffles -> exclusive z arrays
    float x0a = expf(v0), x0b = expf(ALPHA * v0);
    float x1a = expf(v1), x1b = expf(ALPHA * v1);
    float pa = x0a + x1a, pb = x0b + x1b;
    float sa = pa, sb = pb;
    const int lane = t & 63, wid = t >> 6;
#pragma unroll
    for (int off = 1; off < 64; off <<= 1) {
        float ya = __shfl_up(sa, off, 64);
        float yb = __shfl_up(sb, off, 64);
        if (lane >= off) { sa += ya; sb += yb; }
    }
    if (lane == 63) wtot[wid] = make_float2(sa, sb);
    __syncthreads();
    if (t == 0) {
        float ra = 0.f, rb = 0.f;
        for (int w2 = 0; w2 < 16; ++w2) {
            float2 tt = wtot[w2];
            woff[w2] = make_float2(ra, rb);
            ra += tt.x; rb += tt.y;
        }
    }
    __syncthreads();
    float2 o = woff[wid];
    float pre_a = o.x + sa - pa, pre_b = o.y + sb - pb;
    float* Z1 = z1 + b * (NN + 1);
    float* Z2 = z2 + b * (NN + 1);
    if (t == 0) { Z1[0] = 0.f; Z2[0] = 0.f; }
    Z1[2 * t + 1] = pre_a + x0a;  Z2[2 * t + 1] = pre_b + x0b;
    Z1[2 * t + 2] = pre_a + pa;   Z2[2 * t + 2] = pre_b + pb;
}

// ---------------- K_ps: local prefixes + chunk totals + last-block chunk scan -----
__global__ __launch_bounds__(128) void k_ps(const void* __restrict__ text,
                                            const float* __restrict__ e2s,
                                            const int* __restrict__ sidx,
                                            float* __restrict__ PS1,
                                            float* __restrict__ PS2,
                                            float* __restrict__ T1,
                                            float* __restrict__ T2,
                                            int* __restrict__ flag) {
    const int f32 = *flag;
    const int b = blockIdx.x / CHN, ch = blockIdx.x % CHN;
    const int c = threadIdx.x;
    float r1 = 0.f, r2 = 0.f;
    const int k0 = ch * CLEN;
#pragma unroll
    for (int kk = 0; kk < CLEN; ++kk) {
        int k = k0 + kk;
        PS1[(size_t)(b * NN + k) * CC + c] = r1;   // prefix LOCAL to chunk
        PS2[(size_t)(b * NN + k) * CC + c] = r2;
        float v = e2s[b * NN + k];
        int j = sidx[b * NN + k];
        float x = ld1(text, (b * NN + j) * CC + c, f32);
        r1 += expf(v) * x;
        r2 += expf(ALPHA * v) * x;
    }
    T1[(b * (CHN + 1) + ch) * CC + c] = r1;        // chunk totals
    T2[(b * (CHN + 1) + ch) * CC + c] = r2;

    // last block of this batch converts totals -> exclusive bases (+ total at CHN)
    __threadfence();                               // release T writes (device scope)
    __shared__ int amLast;
    if (c == 0) amLast = (atomicAdd(&flag[8 + b], 1) == CHN - 1) ? 1 : 0;
    __syncthreads();
    if (amLast) {
        __threadfence();                           // acquire other blocks' T writes
        float* P1 = T1 + (size_t)(b * (CHN + 1)) * CC + c;
        float* P2 = T2 + (size_t)(b * (CHN + 1)) * CC + c;
        float s1 = 0.f, s2 = 0.f;
        for (int q = 0; q < CHN; q += 8) {
            float a1[8], a2[8];
#pragma unroll
            for (int u = 0; u < 8; ++u) { a1[u] = P1[(q + u) * CC]; a2[u] = P2[(q + u) * CC]; }
#pragma unroll
            for (int u = 0; u < 8; ++u) {
                P1[(q + u) * CC] = s1; s1 += a1[u];
                P2[(q + u) * CC] = s2; s2 += a2[u];
            }
        }
        P1[CHN * CC] = s1;                         // batch totals at slot CHN
        P2[CHN * CC] = s2;
    }
}

// ---------------- K_out: search + combine + MFMA @W (B from global) + elu ---------
__global__ __launch_bounds__(256) void k_out(const void* __restrict__ text,
                                             const ushort* __restrict__ WT,
                                             const float* __restrict__ T1,
                                             const float* __restrict__ T2,
                                             const float* __restrict__ PS1,
                                             const float* __restrict__ PS2,
                                             const float* __restrict__ e1,
                                             const float* __restrict__ e2s,
                                             const float* __restrict__ z1,
                                             const float* __restrict__ z2,
                                             void* __restrict__ out,
                                             const int* __restrict__ flag) {
    __shared__ ushort ul[ROWS * WTPAD];    // 4352 B, bf16 u-tile padded
    __shared__ float4 ri[ROWS];
    const int f32 = *flag;
    const int t = threadIdx.x;
    const int b = blockIdx.x / (NN / ROWS);
    const int r0 = (blockIdx.x % (NN / ROWS)) * ROWS;

    // 16 parallel binary searches
    if (t < ROWS) {
        const int row = b * NN + r0 + t;
        float ev = e1[row];
        float w1 = expf(ev), w2 = expf(ALPHA * ev);
        float thr = -ev;
        const float* e2sb = e2s + b * NN;
        int lo = 0, hi = NN;
        while (lo < hi) {                  // k = #{ j : e2s[j] <= thr }
            int mid = (lo + hi) >> 1;
            if (e2sb[mid] <= thr) lo = mid + 1; else hi = mid;
        }
        float den = w1 * (z1[b * (NN + 1) + NN] - z1[b * (NN + 1) + lo])
                  + w2 * z2[b * (NN + 1) + lo];
        den = fmaxf(den, 1e-30f);
        ri[t] = make_float4(__int_as_float(lo), w1, w2, 1.f / den);
    }
    __syncthreads();

    // phase 1: u[rr][c] = (w1*(S1-P1) + w2*P2)*inv + alpha*text  -> bf16 in LDS
    {
        const int c = t & 127;
        const int g = t >> 7;                 // 0..1 -> rows g*8..g*8+7
        const float* CB1 = T1 + (size_t)(b * (CHN + 1)) * CC + c;
        const float* CB2 = T2 + (size_t)(b * (CHN + 1)) * CC + c;
        const float* B1 = PS1 + (size_t)(b * NN) * CC + c;
        const float* B2 = PS2 + (size_t)(b * NN) * CC + c;
        const float S1 = CB1[CHN * CC];
#pragma unroll
        for (int q = 0; q < 8; ++q) {
            const int rr = g * 8 + q;
            float4 info = ri[rr];
            const int k = __float_as_int(info.x);
            const int c0 = k >> CSH;
            float P1 = CB1[c0 * CC];
            float P2 = CB2[c0 * CC];
            if (k < NN) {                     // local part (k==NN OOB-guard)
                P1 += B1[(size_t)k * CC];
                P2 += B2[(size_t)k * CC];
            }
            float tc = ld1(text, (b * NN + r0 + rr) * CC + c, f32);
            float u = (info.y * (S1 - P1) + info.z * P2) * info.w + ALPHA * tc;
            bf16 ub = __float2bfloat16(u);
            ul[rr * WTPAD + c] = *(const ushort*)&ub;
        }
    }
    __syncthreads();

    // phase 2: out[16 x 128] = elu(u @ W), B-fragments straight from global WT (L2)
    {
        const int wv = t >> 6;
        const int lane = t & 63;
        const int m = lane & 15;
        const int quad = lane >> 4;
        f32x4 acc0 = {0.f, 0.f, 0.f, 0.f};
        f32x4 acc1 = {0.f, 0.f, 0.f, 0.f};
        const int f0 = (wv * 2 + 0) * 16 + m;
        const int f1 = (wv * 2 + 1) * 16 + m;
#pragma unroll
        for (int kt = 0; kt < 4; ++kt) {
            const int ko = kt * 32 + quad * 8;
            short8 afrag = *(const short8*)&ul[m * WTPAD + ko];
            short8 bf0 = *(const short8*)&WT[f0 * CC + ko];
            short8 bf1 = *(const short8*)&WT[f1 * CC + ko];
            acc0 = __builtin_amdgcn_mfma_f32_16x16x32_bf16(afrag, bf0, acc0, 0, 0, 0);
            acc1 = __builtin_amdgcn_mfma_f32_16x16x32_bf16(afrag, bf1, acc1, 0, 0, 0);
        }
        // C/D: col = lane&15 (f within tile), row = quad*4+reg (u-row)
#pragma unroll
        for (int ft = 0; ft < 2; ++ft) {
            f32x4 acc = ft ? acc1 : acc0;
            const int f = (wv * 2 + ft) * 16 + m;
#pragma unroll
            for (int reg = 0; reg < 4; ++reg) {
                const int urow = quad * 4 + reg;
                float x = acc[reg];
                float y = x > 0.f ? x : expm1f(x);
                const int orow = b * NN + r0 + urow;
                if (f32) ((float*)out)[orow * FF + f] = y;
                else     ((bf16*)out)[orow * FF + f] = __float2bfloat16(y);
            }
        }
    }
}

extern "C" void kernel_launch(void* const* d_in, const int* in_sizes, int n_in,
                              void* d_out, int out_size, void* d_ws, size_t ws_size,
                              hipStream_t stream) {
    const void* text = d_in[0];
    const void* Wp   = (n_in >= 4) ? d_in[2] : d_in[1];
    const void* ap   = (n_in >= 4) ? d_in[3] : d_in[2];
    for (int i = 0; i < n_in; ++i) {
        int s = in_sizes[i];
        if (s == BB * NN * CC)      text = d_in[i];
        else if (s == CC * FF)      Wp = d_in[i];
        else if (s == 2 * FF)       ap = d_in[i];
    }

    float* w = (float*)d_ws;
    size_t off = 0;
    int*    flagp  = (int*)(w + off);      off += 16;   // [0]=dtype, [8..15]=done ctrs
    float*  wa1    = w + off;              off += 128;
    float*  wa2    = w + off;              off += 128;
    ushort* WT     = (ushort*)(w + off);   off += 8192;            // 16K bf16
    float*  e1     = w + off;              off += BB * NN;
    float*  e2     = w + off;              off += BB * NN;
    float*  e2s    = w + off;              off += BB * NN;
    int*    sidx   = (int*)(w + off);      off += BB * NN;
    float*  z1     = w + off;              off += BB * (NN + 1);
    float*  z2     = w + off;              off += BB * (NN + 1);
    float*  T1     = w + off;              off += (size_t)BB * (CHN + 1) * CC;
    float*  T2     = w + off;              off += (size_t)BB * (CHN + 1) * CC;
    float*  PS1    = w + off;              off += (size_t)BB * NN * CC;
    float*  PS2    = w + off;              off += (size_t)BB * NN * CC;
    // total ~19.3 MB; ws is ~512 MB (harness fill: 524288 KB)

    k_prep<<<9, 256, 0, stream>>>(text, Wp, ap, flagp, wa1, wa2, WT);
    k_e<<<BB * NN / 4, 256, 0, stream>>>(text, wa1, wa2, e1, e2, flagp);
    k_sort<<<BB, 1024, 0, stream>>>(e2, e2s, sidx, z1, z2);
    k_ps<<<BB * CHN, 128, 0, stream>>>(text, e2s, sidx, PS1, PS2, T1, T2, flagp);
    k_out<<<BB * NN / ROWS, 256, 0, stream>>>(text, WT, T1, T2, PS1, PS2,
                                              e1, e2s, z1, z2, d_out, flagp);
}

// Round 8
// 246.889 us; speedup vs baseline: 1.3523x; 1.3523x over previous
//
#include <hip/hip_runtime.h>
#include <hip/hip_bf16.h>

#define BB 8
#define NN 2048
#define CC 128
#define FF 128
#define ALPHA 0.2f
#define ROWS 16        // rows per k_out block
#define WTPAD 136      // padded LDS row stride in ushorts (272 B)
#define CHN 256        // chunks per batch
#define CLEN 8         // NN/CHN
#define CSH 3          // log2(CLEN)

typedef __hip_bfloat16 bf16;
typedef __attribute__((ext_vector_type(8))) short short8;   // 8 bf16 MFMA operand
typedef __attribute__((ext_vector_type(4))) float f32x4;    // MFMA accumulator

// ---------------- dtype helpers ----------------
__device__ __forceinline__ float ld1(const void* p, int i, int f32) {
    if (f32) return ((const float*)p)[i];
    return __bfloat162float(((const bf16*)p)[i]);
}
__device__ __forceinline__ float2 ld2(const void* p, int pair, int f32) {
    if (f32) return ((const float2*)p)[pair];
    __hip_bfloat162 v = ((const __hip_bfloat162*)p)[pair];
    return make_float2(__bfloat162float(v.x), __bfloat162float(v.y));
}

// ---------------- K_prep: flag + wa + WT(bf16, f-major) ----------------
__global__ __launch_bounds__(256) void k_prep(const void* __restrict__ text,
                                              const void* __restrict__ W,
                                              const void* __restrict__ a,
                                              int* __restrict__ flag,
                                              float* __restrict__ wa1,
                                              float* __restrict__ wa2,
                                              ushort* __restrict__ WT) {
    __shared__ int cnt;
    __shared__ float aL[2 * FF];
    const int t = threadIdx.x;
    if (t == 0) cnt = 0;
    __syncthreads();
    // dtype probe: fp32 low-half words decode as huge bf16 values
    const ushort2* p = (const ushort2*)text;
    int local = 0;
    for (int i = t; i < 1024; i += 256) {
        ushort2 v = p[i];
        float f = __uint_as_float(((unsigned)v.x) << 16);
        if (!(fabsf(f) <= 100.f)) local++;
    }
    atomicAdd(&cnt, local);
    __syncthreads();
    const int f32 = (cnt >= 64) ? 1 : 0;

    if (blockIdx.x == 0) {
        if (t == 0) flag[0] = f32;
        aL[t] = ld1(a, t, f32);                    // t < 256 = 2F
        __syncthreads();
        if (t < CC) {
            float s1 = 0.f, s2 = 0.f;
            for (int f = 0; f < FF; f += 4) {
                float w0 = ld1(W, t * FF + f, f32);
                float w1 = ld1(W, t * FF + f + 1, f32);
                float w2 = ld1(W, t * FF + f + 2, f32);
                float w3 = ld1(W, t * FF + f + 3, f32);
                s1 += w0 * aL[f] + w1 * aL[f + 1] + w2 * aL[f + 2] + w3 * aL[f + 3];
                s2 += w0 * aL[FF + f] + w1 * aL[FF + f + 1] + w2 * aL[FF + f + 2] + w3 * aL[FF + f + 3];
            }
            wa1[t] = s1; wa2[t] = s2;
        }
    } else {
        // WT[f*CC+cc] = bf16(W[cc*FF+f])
        const int base = (blockIdx.x - 1) * 2048;
        for (int i = 0; i < 8; ++i) {
            int idx = base + i * 256 + t;          // idx = cc*FF + f
            int cc = idx >> 7, f = idx & 127;
            float v = ld1(W, idx, f32);
            bf16 b = __float2bfloat16(v);
            WT[f * CC + cc] = *(const ushort*)&b;
        }
    }
}

// ---------------- K_e: e1/e2 per row (wave per row) ----------------
__global__ __launch_bounds__(256) void k_e(const void* __restrict__ text,
                                           const float* __restrict__ wa1,
                                           const float* __restrict__ wa2,
                                           float* __restrict__ e1,
                                           float* __restrict__ e2,
                                           const int* __restrict__ flag) {
    const int f32 = *flag;
    const int wave = threadIdx.x >> 6;
    const int lane = threadIdx.x & 63;
    const int row = blockIdx.x * 4 + wave;
    float2 tv = ld2(text, row * (CC / 2) + lane, f32);
    float s1 = tv.x * wa1[2 * lane] + tv.y * wa1[2 * lane + 1];
    float s2 = tv.x * wa2[2 * lane] + tv.y * wa2[2 * lane + 1];
#pragma unroll
    for (int off = 32; off > 0; off >>= 1) {
        s1 += __shfl_down(s1, off, 64);
        s2 += __shfl_down(s2, off, 64);
    }
    if (lane == 0) { e1[row] = s1; e2[row] = s2; }
}

// ---------------- K_sort: LDS bitonic sort + wave-shuffle scans ----------------
__global__ __launch_bounds__(1024) void k_sort(const float* __restrict__ e2,
                                               float* __restrict__ e2s,
                                               int* __restrict__ sidx,
                                               float* __restrict__ z1,
                                               float* __restrict__ z2) {
    __shared__ float vals[NN];
    __shared__ int   idxs[NN];
    __shared__ float2 wtot[16];
    __shared__ float2 woff[16];
    const int b = blockIdx.x;
    const int t = threadIdx.x;

    for (int i = t; i < NN; i += 1024) { vals[i] = e2[b * NN + i]; idxs[i] = i; }
    __syncthreads();

    for (int size = 2; size <= NN; size <<= 1) {
        for (int stride = size >> 1; stride > 0; stride >>= 1) {
            int i = ((t & ~(stride - 1)) << 1) | (t & (stride - 1));
            int j = i | stride;
            bool up = ((i & size) == 0);
            float vi = vals[i], vj = vals[j];
            bool sw = up ? (vi > vj) : (vi < vj);
            if (sw) {
                vals[i] = vj; vals[j] = vi;
                int ti = idxs[i]; idxs[i] = idxs[j]; idxs[j] = ti;
            }
            __syncthreads();
        }
    }

    float v0 = vals[2 * t], v1 = vals[2 * t + 1];
    e2s[b * NN + 2 * t] = v0;
    e2s[b * NN + 2 * t + 1] = v1;
    sidx[b * NN + 2 * t] = idxs[2 * t];
    sidx[b * NN + 2 * t + 1] = idxs[2 * t + 1];

    // dual inclusive scan (exp(v), exp(.2v)) via wave shuffles -> exclusive z arrays
    float x0a = expf(v0), x0b = expf(ALPHA * v0);
    float x1a = expf(v1), x1b = expf(ALPHA * v1);
    float pa = x0a + x1a, pb = x0b + x1b;
    float sa = pa, sb = pb;
    const int lane = t & 63, wid = t >> 6;
#pragma unroll
    for (int off = 1; off < 64; off <<= 1) {
        float ya = __shfl_up(sa, off, 64);
        float yb = __shfl_up(sb, off, 64);
        if (lane >= off) { sa += ya; sb += yb; }
    }
    if (lane == 63) wtot[wid] = make_float2(sa, sb);
    __syncthreads();
    if (t == 0) {
        float ra = 0.f, rb = 0.f;
        for (int w2 = 0; w2 < 16; ++w2) {
            float2 tt = wtot[w2];
            woff[w2] = make_float2(ra, rb);
            ra += tt.x; rb += tt.y;
        }
    }
    __syncthreads();
    float2 o = woff[wid];
    float pre_a = o.x + sa - pa, pre_b = o.y + sb - pb;
    float* Z1 = z1 + b * (NN + 1);
    float* Z2 = z2 + b * (NN + 1);
    if (t == 0) { Z1[0] = 0.f; Z2[0] = 0.f; }
    Z1[2 * t + 1] = pre_a + x0a;  Z2[2 * t + 1] = pre_b + x0b;
    Z1[2 * t + 2] = pre_a + pa;   Z2[2 * t + 2] = pre_b + pb;
}

// ---------------- K_ps: local prefixes + chunk totals (NO fence/atomic tail) ------
__global__ __launch_bounds__(128) void k_ps(const void* __restrict__ text,
                                            const float* __restrict__ e2s,
                                            const int* __restrict__ sidx,
                                            float* __restrict__ PS1,
                                            float* __restrict__ PS2,
                                            float* __restrict__ T1,
                                            float* __restrict__ T2,
                                            const int* __restrict__ flag) {
    const int f32 = *flag;
    const int b = blockIdx.x / CHN, ch = blockIdx.x % CHN;
    const int c = threadIdx.x;
    float r1 = 0.f, r2 = 0.f;
    const int k0 = ch * CLEN;
#pragma unroll
    for (int kk = 0; kk < CLEN; ++kk) {
        int k = k0 + kk;
        PS1[(size_t)(b * NN + k) * CC + c] = r1;   // prefix LOCAL to chunk
        PS2[(size_t)(b * NN + k) * CC + c] = r2;
        float v = e2s[b * NN + k];
        int j = sidx[b * NN + k];
        float x = ld1(text, (b * NN + j) * CC + c, f32);
        r1 += expf(v) * x;
        r2 += expf(ALPHA * v) * x;
    }
    T1[(b * (CHN + 1) + ch) * CC + c] = r1;        // chunk totals
    T2[(b * (CHN + 1) + ch) * CC + c] = r2;
}

// ---------------- K_scanT: exclusive scan of chunk totals -> chunk bases ----------
__global__ __launch_bounds__(256) void k_scanT(float* __restrict__ T1,
                                               float* __restrict__ T2) {
    const int tid = blockIdx.x * 256 + threadIdx.x;   // 0..B*C-1
    const int b = tid / CC, c = tid % CC;
    float* P1 = T1 + (size_t)(b * (CHN + 1)) * CC + c;
    float* P2 = T2 + (size_t)(b * (CHN + 1)) * CC + c;
    float r1 = 0.f, r2 = 0.f;
    for (int ch = 0; ch < CHN; ch += 8) {
        float t1[8], t2[8];
#pragma unroll
        for (int u = 0; u < 8; ++u) { t1[u] = P1[(ch + u) * CC]; t2[u] = P2[(ch + u) * CC]; }
#pragma unroll
        for (int u = 0; u < 8; ++u) {
            P1[(ch + u) * CC] = r1; r1 += t1[u];
            P2[(ch + u) * CC] = r2; r2 += t2[u];
        }
    }
    P1[CHN * CC] = r1;   // totals at slot CHN
    P2[CHN * CC] = r2;
}

// ---------------- K_out: search + combine + MFMA @W (B from global) + elu ---------
__global__ __launch_bounds__(256) void k_out(const void* __restrict__ text,
                                             const ushort* __restrict__ WT,
                                             const float* __restrict__ T1,
                                             const float* __restrict__ T2,
                                             const float* __restrict__ PS1,
                                             const float* __restrict__ PS2,
                                             const float* __restrict__ e1,
                                             const float* __restrict__ e2s,
                                             const float* __restrict__ z1,
                                             const float* __restrict__ z2,
                                             void* __restrict__ out,
                                             const int* __restrict__ flag) {
    __shared__ ushort ul[ROWS * WTPAD];    // 4352 B, bf16 u-tile padded
    __shared__ float4 ri[ROWS];
    const int f32 = *flag;
    const int t = threadIdx.x;
    const int b = blockIdx.x / (NN / ROWS);
    const int r0 = (blockIdx.x % (NN / ROWS)) * ROWS;

    // 16 parallel binary searches
    if (t < ROWS) {
        const int row = b * NN + r0 + t;
        float ev = e1[row];
        float w1 = expf(ev), w2 = expf(ALPHA * ev);
        float thr = -ev;
        const float* e2sb = e2s + b * NN;
        int lo = 0, hi = NN;
        while (lo < hi) {                  // k = #{ j : e2s[j] <= thr }
            int mid = (lo + hi) >> 1;
            if (e2sb[mid] <= thr) lo = mid + 1; else hi = mid;
        }
        float den = w1 * (z1[b * (NN + 1) + NN] - z1[b * (NN + 1) + lo])
                  + w2 * z2[b * (NN + 1) + lo];
        den = fmaxf(den, 1e-30f);
        ri[t] = make_float4(__int_as_float(lo), w1, w2, 1.f / den);
    }
    __syncthreads();

    // phase 1: u[rr][c] = (w1*(S1-P1) + w2*P2)*inv + alpha*text  -> bf16 in LDS
    {
        const int c = t & 127;
        const int g = t >> 7;                 // 0..1 -> rows g*8..g*8+7
        const float* CB1 = T1 + (size_t)(b * (CHN + 1)) * CC + c;
        const float* CB2 = T2 + (size_t)(b * (CHN + 1)) * CC + c;
        const float* B1 = PS1 + (size_t)(b * NN) * CC + c;
        const float* B2 = PS2 + (size_t)(b * NN) * CC + c;
        const float S1 = CB1[CHN * CC];
#pragma unroll
        for (int q = 0; q < 8; ++q) {
            const int rr = g * 8 + q;
            float4 info = ri[rr];
            const int k = __float_as_int(info.x);
            const int c0 = k >> CSH;
            float P1 = CB1[c0 * CC];
            float P2 = CB2[c0 * CC];
            if (k < NN) {                     // local part (k==NN OOB-guard)
                P1 += B1[(size_t)k * CC];
                P2 += B2[(size_t)k * CC];
            }
            float tc = ld1(text, (b * NN + r0 + rr) * CC + c, f32);
            float u = (info.y * (S1 - P1) + info.z * P2) * info.w + ALPHA * tc;
            bf16 ub = __float2bfloat16(u);
            ul[rr * WTPAD + c] = *(const ushort*)&ub;
        }
    }
    __syncthreads();

    // phase 2: out[16 x 128] = elu(u @ W), B-fragments straight from global WT (L2)
    {
        const int wv = t >> 6;
        const int lane = t & 63;
        const int m = lane & 15;
        const int quad = lane >> 4;
        f32x4 acc0 = {0.f, 0.f, 0.f, 0.f};
        f32x4 acc1 = {0.f, 0.f, 0.f, 0.f};
        const int f0 = (wv * 2 + 0) * 16 + m;
        const int f1 = (wv * 2 + 1) * 16 + m;
#pragma unroll
        for (int kt = 0; kt < 4; ++kt) {
            const int ko = kt * 32 + quad * 8;
            short8 afrag = *(const short8*)&ul[m * WTPAD + ko];
            short8 bf0 = *(const short8*)&WT[f0 * CC + ko];
            short8 bf1 = *(const short8*)&WT[f1 * CC + ko];
            acc0 = __builtin_amdgcn_mfma_f32_16x16x32_bf16(afrag, bf0, acc0, 0, 0, 0);
            acc1 = __builtin_amdgcn_mfma_f32_16x16x32_bf16(afrag, bf1, acc1, 0, 0, 0);
        }
        // C/D: col = lane&15 (f within tile), row = quad*4+reg (u-row)
#pragma unroll
        for (int ft = 0; ft < 2; ++ft) {
            f32x4 acc = ft ? acc1 : acc0;
            const int f = (wv * 2 + ft) * 16 + m;
#pragma unroll
            for (int reg = 0; reg < 4; ++reg) {
                const int urow = quad * 4 + reg;
                float x = acc[reg];
                float y = x > 0.f ? x : expm1f(x);
                const int orow = b * NN + r0 + urow;
                if (f32) ((float*)out)[orow * FF + f] = y;
                else     ((bf16*)out)[orow * FF + f] = __float2bfloat16(y);
            }
        }
    }
}

extern "C" void kernel_launch(void* const* d_in, const int* in_sizes, int n_in,
                              void* d_out, int out_size, void* d_ws, size_t ws_size,
                              hipStream_t stream) {
    const void* text = d_in[0];
    const void* Wp   = (n_in >= 4) ? d_in[2] : d_in[1];
    const void* ap   = (n_in >= 4) ? d_in[3] : d_in[2];
    for (int i = 0; i < n_in; ++i) {
        int s = in_sizes[i];
        if (s == BB * NN * CC)      text = d_in[i];
        else if (s == CC * FF)      Wp = d_in[i];
        else if (s == 2 * FF)       ap = d_in[i];
    }

    float* w = (float*)d_ws;
    size_t off = 0;
    int*    flagp  = (int*)(w + off);      off += 16;
    float*  wa1    = w + off;              off += 128;
    float*  wa2    = w + off;              off += 128;
    ushort* WT     = (ushort*)(w + off);   off += 8192;            // 16K bf16
    float*  e1     = w + off;              off += BB * NN;
    float*  e2     = w + off;              off += BB * NN;
    float*  e2s    = w + off;              off += BB * NN;
    int*    sidx   = (int*)(w + off);      off += BB * NN;
    float*  z1     = w + off;              off += BB * (NN + 1);
    float*  z2     = w + off;              off += BB * (NN + 1);
    float*  T1     = w + off;              off += (size_t)BB * (CHN + 1) * CC;
    float*  T2     = w + off;              off += (size_t)BB * (CHN + 1) * CC;
    float*  PS1    = w + off;              off += (size_t)BB * NN * CC;
    float*  PS2    = w + off;              off += (size_t)BB * NN * CC;
    // total ~19.3 MB; ws is ~512 MB (harness fill: 524288 KB)

    k_prep<<<9, 256, 0, stream>>>(text, Wp, ap, flagp, wa1, wa2, WT);
    k_e<<<BB * NN / 4, 256, 0, stream>>>(text, wa1, wa2, e1, e2, flagp);
    k_sort<<<BB, 1024, 0, stream>>>(e2, e2s, sidx, z1, z2);
    k_ps<<<BB * CHN, 128, 0, stream>>>(text, e2s, sidx, PS1, PS2, T1, T2, flagp);
    k_scanT<<<4, 256, 0, stream>>>(T1, T2);
    k_out<<<BB * NN / ROWS, 256, 0, stream>>>(text, WT, T1, T2, PS1, PS2,
                                              e1, e2s, z1, z2, d_out, flagp);
}